// Round 14
// baseline (229.929 us; speedup 1.0000x reference)
//
#include <hip/hip_runtime.h>
#include <hip/hip_fp16.h>
#include <math.h>

typedef __attribute__((ext_vector_type(8))) _Float16 f16x8;
typedef __attribute__((ext_vector_type(2))) __fp16 fp16x2;
typedef __attribute__((ext_vector_type(4))) float f32x4;

constexpr int D = 256;           // feature dim (K of GEMM)
constexpr int H = 128;           // hidden dim
constexpr int KSTEPS = D / 32;   // 8 MFMA k-steps
constexpr int BM = 32;           // rows per block (N = 300000 = 32 * 9375)

union FragH { uint4 u; f16x8 f; };
union H2U { fp16x2 h; unsigned int u; };

__device__ __forceinline__ unsigned int pkrtz(float a, float b) {
  H2U r; r.h = __builtin_amdgcn_cvt_pkrtz(a, b); return r.u;
}

__device__ __forceinline__ void gload16(const void* g, void* l) {
  __builtin_amdgcn_global_load_lds(
      (const __attribute__((address_space(1))) unsigned int*)g,
      (__attribute__((address_space(3))) unsigned int*)l, 16, 0, 0);
}
__device__ __forceinline__ void block_sync() {
  asm volatile("" ::: "memory");
  __builtin_amdgcn_s_barrier();
  asm volatile("" ::: "memory");
}

// ---- init: zero d_out + Z accumulator --------------------------------------
extern "C" __global__ void __launch_bounds__(256)
k_init(float* __restrict__ out, int out_size, float* __restrict__ zacc)
{
  const int i = blockIdx.x * 256 + threadIdx.x;
  if (i < out_size) out[i] = 0.0f;
  if (i == 0) *zacc = 0.0f;
}

// ---- Pre-pack W1 into per-lane MFMA B-fragment order (fp16 RTN) ------------
// Index g = (kstep*8 + htile)*64 + lane; element j: K = kstep*32+(lane>>4)*8+j,
// N(col) = htile*16 + (lane&15).
extern "C" __global__ void __launch_bounds__(256)
k_pack(const float* __restrict__ W1, uint4* __restrict__ pw)
{
  const int g = blockIdx.x * 256 + threadIdx.x;       // 0..4095
  const int c = g >> 9, ht = (g >> 6) & 7, l = g & 63;
  const int kbase = c * 32 + (l >> 4) * 8;
  const int col = ht * 16 + (l & 15);
  unsigned short q[8];
#pragma unroll
  for (int i = 0; i < 8; ++i) {
    const float v = W1[(size_t)(kbase + i) * H + col];
    const __half hh = __float2half(v);                 // RTN
    q[i] = __half_as_ushort(hh);
  }
  uint4 h4;
  h4.x = (unsigned)q[0] | ((unsigned)q[1] << 16);
  h4.y = (unsigned)q[2] | ((unsigned)q[3] << 16);
  h4.z = (unsigned)q[4] | ((unsigned)q[5] << 16);
  h4.w = (unsigned)q[6] | ((unsigned)q[7] << 16);
  pw[g] = h4;
}

// ---- Fused: contiguous-row staging + fp16 MFMA + pooling -------------------
// BM=32. Stage: each wave issues 8 gload16, ONE PER FULL ROW (1 KB contiguous
// per instruction — the HBM-friendly granule), back-to-back, single
// vmcnt(0)+barrier. Source bytes within the row are XOR-permuted
// (chunk l ^ (row&7)) so LDS (linear dest, rule 21) ends up swizzled and the
// fragment reads are ~2-way instead of 16-way bank-conflicted.
// K-loop: barrier-free (tile read-only), A+B prefetch 1 kstep ahead.
// 4 waves (rg,cg): rows rg*16..+15 x hidden cols cg*64..+63.
extern "C" __global__ void __launch_bounds__(256, 4)
k_fused(const float* __restrict__ x, const int* __restrict__ batch,
        const uint4* __restrict__ pw, const float* __restrict__ b1,
        const float* __restrict__ W2, const float* __restrict__ b2,
        float* __restrict__ out, float* __restrict__ zacc, int N)
{
  __shared__ float4 xtile4[BM * 64];   // 32 KB: row-major rows, chunks XOR-swz
  __shared__ float sred[2][BM];        // cross-wave epilogue partials
  __shared__ float wlds[BM];           // per-row unnormalized weights

  const int t = threadIdx.x;
  const int l = t & 63;
  const int w = t >> 6;
  const int lg = l >> 4;      // k-group (0..3)
  const int lr = l & 15;      // M-row (A) / N-col (B,C)
  const int rg = w >> 1;      // row half (0..1)
  const int cg = w & 1;       // col half (0..1)
  const int n0 = blockIdx.x * BM;

  const char* xb = (const char*)x;
  char* xt = (char*)xtile4;

  // W fragments for kstep 0: issue before staging (drained by same vmcnt(0))
  FragH bw[4], nbw[4];
#pragma unroll
  for (int h = 0; h < 4; ++h)
    bw[h].u = pw[(cg * 4 + h) * 64 + l];

  // ---- stage: 8 full-row contiguous loads per wave, no consumption between
#pragma unroll
  for (int i = 0; i < 8; ++i) {
    const int row = w * 8 + i;                         // 0..31
    const int srow = min(n0 + row, N - 1);             // N%32==0: always valid
    const int sch = l ^ (row & 7);                     // within-row source perm
    gload16(xb + (size_t)srow * 1024 + sch * 16, xt + row * 1024 + l * 16);
  }
  asm volatile("s_waitcnt vmcnt(0)" ::: "memory");
  block_sync();

  // ---- k-loop: barrier-free, full-K tile resident --------------------------
  const int arow = rg * 16 + lr;                       // this lane's A row
  const char* arb = xt + arow * 1024;
  const int rx = (arow & 7);                           // read-side XOR
  f32x4 acc[4] = {};                                   // 4 local htiles

  float4 a0 = *(const float4*)(arb + ((lg * 2 + 0) ^ rx) * 16);
  float4 a1 = *(const float4*)(arb + ((lg * 2 + 1) ^ rx) * 16);

#pragma unroll
  for (int c = 0; c < KSTEPS; ++c) {
    float4 na0, na1;
    if (c + 1 < KSTEPS) {
      const int ch0 = (c + 1) * 8 + lg * 2;
      na0 = *(const float4*)(arb + ((ch0 + 0) ^ rx) * 16);
      na1 = *(const float4*)(arb + ((ch0 + 1) ^ rx) * 16);
#pragma unroll
      for (int h = 0; h < 4; ++h)
        nbw[h].u = pw[((c + 1) * 8 + cg * 4 + h) * 64 + l];
    }
    FragH a;
    a.u.x = pkrtz(a0.x, a0.y);
    a.u.y = pkrtz(a0.z, a0.w);
    a.u.z = pkrtz(a1.x, a1.y);
    a.u.w = pkrtz(a1.z, a1.w);
#pragma unroll
    for (int h = 0; h < 4; ++h)
      acc[h] = __builtin_amdgcn_mfma_f32_16x16x32_f16(a.f, bw[h].f, acc[h], 0, 0, 0);
#pragma unroll
    for (int h = 0; h < 4; ++h) bw[h] = nbw[h];
    a0 = na0; a1 = na1;
  }

  // ---- epilogue: relu(h+b1)@W2 partials, cross-wave sum, w = exp(s) --------
  float bvv[4], wvv[4];
#pragma unroll
  for (int h = 0; h < 4; ++h) {
    const int col = (cg * 4 + h) * 16 + lr;
    bvv[h] = b1[col];
    wvv[h] = W2[col];
  }
#pragma unroll
  for (int r = 0; r < 4; ++r) {
    float p = 0.0f;
#pragma unroll
    for (int h = 0; h < 4; ++h)
      p = fmaf(fmaxf(acc[h][r] + bvv[h], 0.0f), wvv[h], p);
#pragma unroll
    for (int off = 1; off < 16; off <<= 1) p += __shfl_xor(p, off, 64);
    if (lr == 0) sred[cg][rg * 16 + lg * 4 + r] = p;
  }
  __syncthreads();
  if (w == 0) {                       // one wave finalizes all 32 rows
    const int row = l & 31;
    const float sc = sred[0][row] + sred[1][row] + b2[0];
    const float wgt = (l < 32) ? __expf(sc) : 0.0f;
    if (l < 32) wlds[row] = wgt;
    float zs = wgt;
#pragma unroll
    for (int off = 1; off < 64; off <<= 1) zs += __shfl_xor(zs, off, 64);
    if (l == 0) atomicAdd(zacc, zs);
  }
  __syncthreads();

  // ---- phase 2: pool own rows (batch sorted); wave w: 8 rows, lane: 4 cols
  {
    const int nStart = n0 + w * 8;
    float4 a4 = make_float4(0.f, 0.f, 0.f, 0.f);
    int bprev = batch[nStart];
#pragma unroll 1
    for (int n = nStart; n < nStart + 8; ++n) {
      const int b = batch[n];
      if (b != bprev) {
        float* o = out + (size_t)bprev * D + l * 4;
        atomicAdd(o + 0, a4.x); atomicAdd(o + 1, a4.y);
        atomicAdd(o + 2, a4.z); atomicAdd(o + 3, a4.w);
        a4 = make_float4(0.f, 0.f, 0.f, 0.f);
        bprev = b;
      }
      const float wgt = wlds[n - n0];
      const float4 xv = *reinterpret_cast<const float4*>(x + (size_t)n * D + l * 4);
      a4.x = fmaf(xv.x, wgt, a4.x);
      a4.y = fmaf(xv.y, wgt, a4.y);
      a4.z = fmaf(xv.z, wgt, a4.z);
      a4.w = fmaf(xv.w, wgt, a4.w);
    }
    float* o = out + (size_t)bprev * D + l * 4;
    atomicAdd(o + 0, a4.x); atomicAdd(o + 1, a4.y);
    atomicAdd(o + 2, a4.z); atomicAdd(o + 3, a4.w);
  }
}

// ---- finish: out *= 1/Z ----------------------------------------------------
extern "C" __global__ void __launch_bounds__(256)
k_finish(float* __restrict__ out, const float* __restrict__ zacc, int size)
{
  const int i = blockIdx.x * 256 + threadIdx.x;
  if (i < size) out[i] *= (1.0f / *zacc);
}

extern "C" void kernel_launch(void* const* d_in, const int* in_sizes, int n_in,
                              void* d_out, int out_size, void* d_ws, size_t ws_size,
                              hipStream_t stream)
{
  const float* x     = (const float*)d_in[0];
  const int*   batch = (const int*)d_in[1];
  const float* W1 = (const float*)d_in[3];
  const float* b1 = (const float*)d_in[4];
  const float* W2 = (const float*)d_in[5];
  const float* b2 = (const float*)d_in[6];
  const int N = in_sizes[1];

  float* zacc = (float*)d_ws;
  uint4* pw   = (uint4*)((char*)d_ws + 256);            // 64 KB fp16 W frags

  k_init<<<(out_size + 255) / 256, 256, 0, stream>>>((float*)d_out, out_size, zacc);
  k_pack<<<16, 256, 0, stream>>>(W1, pw);

  const int g1 = (N + BM - 1) / BM;
  k_fused<<<g1, 256, 0, stream>>>(x, batch, pw, b1, W2, b2,
                                  (float*)d_out, zacc, N);

  k_finish<<<(out_size + 255) / 256, 256, 0, stream>>>((float*)d_out, zacc, out_size);
}